// Round 6
// baseline (221.580 us; speedup 1.0000x reference)
//
#include <hip/hip_runtime.h>
#include <hip/hip_bf16.h>

#define Bc 2
#define Hc 16
#define Sc 2048
#define Dc 1024

typedef __attribute__((ext_vector_type(8))) short s16x8;
typedef __attribute__((ext_vector_type(4))) float f32x4;

#if __has_builtin(__builtin_amdgcn_exp2f)
#define EXP2(x) __builtin_amdgcn_exp2f(x)
#else
#define EXP2(x) exp2f(x)
#endif

static __device__ __forceinline__ unsigned short f2bf(float f) {
    union { float f; unsigned u; } x; x.f = f;
    unsigned r = x.u + 0x7fffu + ((x.u >> 16) & 1u);
    return (unsigned short)(r >> 16);
}

// ReLU + scale + fp32->bf16 + [B,S,D] -> [B*H, S, 64] head-major relayout
__global__ __launch_bounds__(256) void relu_cvt_heads(const float* __restrict__ src,
                                                      unsigned short* __restrict__ dst,
                                                      float scale) {
    long i = ((long)blockIdx.x * blockDim.x + threadIdx.x) * 4;
    if (i >= (long)Bc * Sc * Dc) return;
    int dh = (int)(i & 63);
    int h  = (int)((i >> 6) & (Hc - 1));
    int s  = (int)((i >> 10) & (Sc - 1));
    int b  = (int)(i >> 21);
    float4 v = *reinterpret_cast<const float4*>(src + i);
    long o = (((long)b * Hc + h) * Sc + s) * 64 + dh;
    ushort4 w;
    w.x = f2bf(fmaxf(v.x, 0.f) * scale);
    w.y = f2bf(fmaxf(v.y, 0.f) * scale);
    w.z = f2bf(fmaxf(v.z, 0.f) * scale);
    w.w = f2bf(fmaxf(v.w, 0.f) * scale);
    *reinterpret_cast<ushort4*>(dst + o) = w;
}

// ReLU + cvt + transpose V: [B,S,D] -> VT[B*H][64 dh][S] bf16 (tiled via LDS)
__global__ __launch_bounds__(256) void relu_cvt_vT(const float* __restrict__ v,
                                                   unsigned short* __restrict__ vt) {
    __shared__ unsigned short lds[64][66];   // [s][dh], stride 66 (conflict-break)
    const int tid = threadIdx.x;
    const int st = blockIdx.x & (Sc / 64 - 1);   // 32 s-tiles
    const int bh = blockIdx.x >> 5;
    const int b = bh >> 4, h = bh & 15;
#pragma unroll
    for (int i = 0; i < 4; ++i) {
        int srow = (tid >> 4) + i * 16;
        int scol = (tid & 15) * 4;
        float4 x = *(const float4*)(v + ((long)b * Sc + st * 64 + srow) * Dc + h * 64 + scol);
        lds[srow][scol + 0] = f2bf(fmaxf(x.x, 0.f));
        lds[srow][scol + 1] = f2bf(fmaxf(x.y, 0.f));
        lds[srow][scol + 2] = f2bf(fmaxf(x.z, 0.f));
        lds[srow][scol + 3] = f2bf(fmaxf(x.w, 0.f));
    }
    __syncthreads();
#pragma unroll
    for (int i = 0; i < 2; ++i) {
        int dh = (tid >> 3) + i * 32;
        int sc = (tid & 7) * 8;
        union { unsigned short u[8]; s16x8 v8; } o;
#pragma unroll
        for (int j = 0; j < 8; ++j) o.u[j] = lds[sc + j][dh];
        *(s16x8*)(vt + ((long)bh * 64 + dh) * Sc + st * 64 + sc) = o.v8;
    }
}

// plain fp32->bf16 (for W)
__global__ __launch_bounds__(256) void cvt_w(const float* __restrict__ src,
                                             unsigned short* __restrict__ dst) {
    long i = ((long)blockIdx.x * blockDim.x + threadIdx.x) * 4;
    if (i >= (long)Dc * Dc) return;
    float4 v = *reinterpret_cast<const float4*>(src + i);
    ushort4 w;
    w.x = f2bf(v.x); w.y = f2bf(v.y); w.z = f2bf(v.z); w.w = f2bf(v.w);
    *reinterpret_cast<ushort4*>(dst + i) = w;
}

// Flash attention, swapped-operand, static softmax max (q,k ReLU'd => scores in
// [0,~7.2] exp2-domain). 4 waves/block, each wave covers a 512-key KV quarter of
// the SAME QBLK=32 q-tile; partials merged additively via LDS (static max => no
// rescale). XCD-swizzled: 256 consecutive jobs (4 bh, 2MB K/V) per XCD L2.
// S^T = K·Q^T (C: row=kv, col=q=lane&15); O^T = V^T·P^T (C: row=dh, col=q).
__global__ __launch_bounds__(256) void attn32x4(const unsigned short* __restrict__ qh,
                                                const unsigned short* __restrict__ kh,
                                                const unsigned short* __restrict__ vt,
                                                unsigned short* __restrict__ xout) {
    __shared__ float Osum[4][2][4][4][64];   // [wave][qi][d][j][lane] 32KB
    __shared__ float Dsum[4][2][16];         // [wave][qi][r]

    const int tid = threadIdx.x;
    const int l = tid & 63, w = tid >> 6;
    const int r = l & 15, g = l >> 4;
    // XCD swizzle (bijective: 2048 % 8 == 0)
    const int job = (blockIdx.x & 7) * (2048 / 8) + (blockIdx.x >> 3);
    const int qt = job & (Sc / 32 - 1);   // 64 q-blocks per bh
    const int bh = job >> 6;

    const unsigned short* Qp = qh + ((long)bh * Sc + qt * 32) * 64;
    const unsigned short* Kp = kh + (long)bh * Sc * 64;
    const unsigned short* Vp = vt + (long)bh * 64 * Sc;
    const int kvbase = w * (Sc / 4);      // this wave's 512-key quarter

    // Q^T B-frags (hoisted, same for all 4 waves)
    s16x8 qb[2][2];
#pragma unroll
    for (int qi = 0; qi < 2; ++qi) {
        qb[qi][0] = *(const s16x8*)(Qp + (qi * 16 + r) * 64 + g * 8);
        qb[qi][1] = *(const s16x8*)(Qp + (qi * 16 + r) * 64 + 32 + g * 8);
    }

    f32x4 acc[2][4];
#pragma unroll
    for (int qi = 0; qi < 2; ++qi)
#pragma unroll
        for (int d = 0; d < 4; ++d) acc[qi][d] = (f32x4){0.f, 0.f, 0.f, 0.f};
    float denom[2] = {0.f, 0.f};

    // P^T B-frag shuffle sources: word wd of lane(r,g) comes from
    // lane (2*(g&1)+(wd>>1))*16+r, pk-pair (wd&1), kv-half hi=(g>=2).
    const int srcA = ((g & 1) << 5) + r;   // words 0,1
    const int srcB = srcA + 16;            // words 2,3
    const bool hi = (g >= 2);

    auto ldk = [&](int kv0, s16x8* ka) {
        ka[0] = *(const s16x8*)(Kp + (kv0 + r) * 64 + g * 8);
        ka[1] = *(const s16x8*)(Kp + (kv0 + r) * 64 + 32 + g * 8);
        ka[2] = *(const s16x8*)(Kp + (kv0 + 16 + r) * 64 + g * 8);
        ka[3] = *(const s16x8*)(Kp + (kv0 + 16 + r) * 64 + 32 + g * 8);
    };
    auto ldv = [&](int kv0, s16x8* va) {
#pragma unroll
        for (int d = 0; d < 4; ++d)
            va[d] = *(const s16x8*)(Vp + (d * 16 + r) * Sc + kv0 + g * 8);
    };

    auto step = [&](const s16x8* ka, const s16x8* va) {
#pragma unroll
        for (int qi = 0; qi < 2; ++qi) {
            const f32x4 z = {0.f, 0.f, 0.f, 0.f};
            f32x4 st0 = __builtin_amdgcn_mfma_f32_16x16x32_bf16(ka[1], qb[qi][1], z, 0, 0, 0);
            st0 = __builtin_amdgcn_mfma_f32_16x16x32_bf16(ka[0], qb[qi][0], st0, 0, 0, 0);
            f32x4 st1 = __builtin_amdgcn_mfma_f32_16x16x32_bf16(ka[3], qb[qi][1], z, 0, 0, 0);
            st1 = __builtin_amdgcn_mfma_f32_16x16x32_bf16(ka[2], qb[qi][0], st1, 0, 0, 0);
            // static-max softmax numerators, single v_exp_f32 each
            float e00 = EXP2(st0[0]), e01 = EXP2(st0[1]);
            float e02 = EXP2(st0[2]), e03 = EXP2(st0[3]);
            float e10 = EXP2(st1[0]), e11 = EXP2(st1[1]);
            float e12 = EXP2(st1[2]), e13 = EXP2(st1[3]);
            denom[qi] += ((e00 + e01) + (e02 + e03)) + ((e10 + e11) + (e12 + e13));
            // bf16 pack via round-bit + v_perm (hi16 of each f32), pairs along kv
            unsigned u00 = __builtin_bit_cast(unsigned, e00) + 0x8000u;
            unsigned u01 = __builtin_bit_cast(unsigned, e01) + 0x8000u;
            unsigned u02 = __builtin_bit_cast(unsigned, e02) + 0x8000u;
            unsigned u03 = __builtin_bit_cast(unsigned, e03) + 0x8000u;
            unsigned u10 = __builtin_bit_cast(unsigned, e10) + 0x8000u;
            unsigned u11 = __builtin_bit_cast(unsigned, e11) + 0x8000u;
            unsigned u12 = __builtin_bit_cast(unsigned, e12) + 0x8000u;
            unsigned u13 = __builtin_bit_cast(unsigned, e13) + 0x8000u;
            int pk00 = (int)__builtin_amdgcn_perm(u01, u00, 0x07060302u);  // kv 4g,4g+1
            int pk01 = (int)__builtin_amdgcn_perm(u03, u02, 0x07060302u);  // kv 4g+2,4g+3
            int pk10 = (int)__builtin_amdgcn_perm(u11, u10, 0x07060302u);  // kv 16+4g..
            int pk11 = (int)__builtin_amdgcn_perm(u13, u12, 0x07060302u);
            int a0 = __shfl(pk00, srcA), b0 = __shfl(pk01, srcA);
            int a1 = __shfl(pk10, srcA), b1 = __shfl(pk11, srcA);
            int c0 = __shfl(pk00, srcB), d0 = __shfl(pk01, srcB);
            int c1 = __shfl(pk10, srcB), d1 = __shfl(pk11, srcB);
            union { int wd[4]; s16x8 v8; } bp;
            bp.wd[0] = hi ? a1 : a0;
            bp.wd[1] = hi ? b1 : b0;
            bp.wd[2] = hi ? c1 : c0;
            bp.wd[3] = hi ? d1 : d0;
#pragma unroll
            for (int d = 0; d < 4; ++d)
                acc[qi][d] = __builtin_amdgcn_mfma_f32_16x16x32_bf16(va[d], bp.v8, acc[qi][d], 0, 0, 0);
        }
    };

    // register double-buffered loop over this wave's 16 kv-steps
    s16x8 kaA[4], vaA[4], kaB[4], vaB[4];
    ldk(kvbase, kaA); ldv(kvbase, vaA);
    for (int t = 0; t < 16; t += 2) {
        ldk(kvbase + (t + 1) * 32, kaB); ldv(kvbase + (t + 1) * 32, vaB);
        step(kaA, vaA);
        int n2 = kvbase + ((t + 2) & 15) * 32;   // wraps (harmless)
        ldk(n2, kaA); ldv(n2, vaA);
        step(kaB, vaB);
    }

    // ---- cross-wave merge (additive: static max, no rescale) ----
#pragma unroll
    for (int qi = 0; qi < 2; ++qi) {
        float dn = denom[qi];
        dn += __shfl_xor(dn, 16);
        dn += __shfl_xor(dn, 32);   // now uniform over g: per-q (col r) partial
        if (l < 16) Dsum[w][qi][r] = dn;
#pragma unroll
        for (int d = 0; d < 4; ++d)
#pragma unroll
            for (int j = 0; j < 4; ++j)
                Osum[w][qi][d][j][l] = acc[qi][d][j];
    }
    __syncthreads();

    // wave w finalizes dh-tile d == w for both q-tiles
    const int b = bh >> 4, h = bh & 15;
#pragma unroll
    for (int qi = 0; qi < 2; ++qi) {
        const float dtot = Dsum[0][qi][r] + Dsum[1][qi][r] + Dsum[2][qi][r] + Dsum[3][qi][r];
        const float inv = 1.0f / dtot;   // lane-aligned: col q = r
        unsigned short* Xrow = xout + ((long)b * Sc + qt * 32 + qi * 16 + r) * Dc + h * 64;
#pragma unroll
        for (int j = 0; j < 4; ++j) {
            float o = Osum[0][qi][w][j][l] + Osum[1][qi][w][j][l] +
                      Osum[2][qi][w][j][l] + Osum[3][qi][w][j][l];
            Xrow[w * 16 + g * 4 + j] = f2bf(o * inv);
        }
    }
}

// Output projection: out = relu(X @ W^T + b). 4 waves/block, 64x64 tile.
__global__ __launch_bounds__(256) void proj64(const unsigned short* __restrict__ X,
                                              const unsigned short* __restrict__ Wb,
                                              const float* __restrict__ bias,
                                              float* __restrict__ out) {
    const int l = threadIdx.x & 63, wv = threadIdx.x >> 6;
    const int r = l & 15, g = l >> 4;
    const int nb = blockIdx.x & 15;   // N/64
    const int mb = blockIdx.x >> 4;   // M/64
    const unsigned short* Xp = X + ((long)(mb * 64 + wv * 16 + r)) * Dc;
    const unsigned short* W0 = Wb + ((long)(nb * 64 + r)) * Dc;
    f32x4 acc[4];
#pragma unroll
    for (int nt = 0; nt < 4; ++nt) acc[nt] = (f32x4){0.f, 0.f, 0.f, 0.f};
#pragma unroll 2
    for (int k = 0; k < Dc; k += 32) {
        s16x8 a = *(const s16x8*)(Xp + k + g * 8);
#pragma unroll
        for (int nt = 0; nt < 4; ++nt) {
            s16x8 bf = *(const s16x8*)(W0 + (long)nt * 16 * Dc + k + g * 8);
            acc[nt] = __builtin_amdgcn_mfma_f32_16x16x32_bf16(a, bf, acc[nt], 0, 0, 0);
        }
    }
#pragma unroll
    for (int nt = 0; nt < 4; ++nt) {
        const float bv = bias[nb * 64 + nt * 16 + r];
#pragma unroll
        for (int j = 0; j < 4; ++j)
            out[((long)(mb * 64 + wv * 16 + g * 4 + j)) * Dc + nb * 64 + nt * 16 + r] =
                fmaxf(acc[nt][j] + bv, 0.f);
    }
}

extern "C" void kernel_launch(void* const* d_in, const int* in_sizes, int n_in,
                              void* d_out, int out_size, void* d_ws, size_t ws_size,
                              hipStream_t stream) {
    const float* q    = (const float*)d_in[0];
    const float* k    = (const float*)d_in[1];
    const float* v    = (const float*)d_in[2];
    const float* w    = (const float*)d_in[3];
    const float* bias = (const float*)d_in[4];
    float* out = (float*)d_out;

    unsigned short* ws = (unsigned short*)d_ws;
    unsigned short* qh = ws;                   // 4194304 bf16
    unsigned short* kh = qh + 4194304;
    unsigned short* vt = kh + 4194304;         // V^T: [B*H][64][2048]
    unsigned short* wb = vt + 4194304;         // 1048576 bf16
    unsigned short* X  = wb + 1048576;         // 4194304 bf16

    // fold softmax scale (1/sqrt(64)) and log2(e) into Q: scores in exp2 domain
    const float QSCALE = 0.125f * 1.44269504088896340736f;
    relu_cvt_heads<<<4096, 256, 0, stream>>>(q, qh, QSCALE);
    relu_cvt_heads<<<4096, 256, 0, stream>>>(k, kh, 1.0f);
    relu_cvt_vT<<<1024, 256, 0, stream>>>(v, vt);
    cvt_w<<<1024, 256, 0, stream>>>(w, wb);
    attn32x4<<<Bc * Hc * (Sc / 32), 256, 0, stream>>>(qh, kh, vt, X);
    proj64<<<(Bc * Sc / 64) * (Dc / 64), 256, 0, stream>>>(X, wb, bias, out);
}

// Round 7
// 213.803 us; speedup vs baseline: 1.0364x; 1.0364x over previous
//
#include <hip/hip_runtime.h>
#include <hip/hip_bf16.h>

#define Bc 2
#define Hc 16
#define Sc 2048
#define Dc 1024

typedef __attribute__((ext_vector_type(8))) short s16x8;
typedef __attribute__((ext_vector_type(4))) float f32x4;
typedef __attribute__((ext_vector_type(16))) float f32x16;

static __device__ __forceinline__ float fexp2(float x) {
#if __has_builtin(__builtin_amdgcn_exp2f)
    return __builtin_amdgcn_exp2f(x);
#else
    float r; asm("v_exp_f32 %0, %1" : "=v"(r) : "v"(x)); return r;
#endif
}

// pack two f32 -> one u32 of 2 bf16 (RTNE), single instruction (T12)
static __device__ __forceinline__ unsigned cvtpk(float lo, float hi) {
    unsigned r; asm("v_cvt_pk_bf16_f32 %0, %1, %2" : "=v"(r) : "v"(lo), "v"(hi));
    return r;
}

// exchange x.lanes[32:63] <-> y.lanes[0:31] (cross-half move), one instr each way
static __device__ __forceinline__ void plswap(unsigned &x, unsigned &y) {
#if __has_builtin(__builtin_amdgcn_permlane32_swap)
    typedef __attribute__((ext_vector_type(2))) unsigned int u32x2;
    u32x2 t = __builtin_amdgcn_permlane32_swap(x, y, false, false);
    x = t.x; y = t.y;
#else
    asm volatile("v_permlane32_swap_b32 %0, %1" : "+v"(x), "+v"(y));
#endif
}

static __device__ __forceinline__ unsigned short f2bf(float f) {
    union { float f; unsigned u; } x; x.f = f;
    unsigned r = x.u + 0x7fffu + ((x.u >> 16) & 1u);
    return (unsigned short)(r >> 16);
}

// ReLU + scale + fp32->bf16 + [B,S,D] -> [B*H, S, 64] head-major relayout
__global__ __launch_bounds__(256) void relu_cvt_heads(const float* __restrict__ src,
                                                      unsigned short* __restrict__ dst,
                                                      float scale) {
    long i = ((long)blockIdx.x * blockDim.x + threadIdx.x) * 4;
    if (i >= (long)Bc * Sc * Dc) return;
    int dh = (int)(i & 63);
    int h  = (int)((i >> 6) & (Hc - 1));
    int s  = (int)((i >> 10) & (Sc - 1));
    int b  = (int)(i >> 21);
    float4 v = *reinterpret_cast<const float4*>(src + i);
    long o = (((long)b * Hc + h) * Sc + s) * 64 + dh;
    ushort4 w;
    w.x = f2bf(fmaxf(v.x, 0.f) * scale);
    w.y = f2bf(fmaxf(v.y, 0.f) * scale);
    w.z = f2bf(fmaxf(v.z, 0.f) * scale);
    w.w = f2bf(fmaxf(v.w, 0.f) * scale);
    *reinterpret_cast<ushort4*>(dst + o) = w;
}

// ReLU + cvt + transpose V: [B,S,D] -> VT[B*H][64 dh][S] bf16 (tiled via LDS)
__global__ __launch_bounds__(256) void relu_cvt_vT(const float* __restrict__ v,
                                                   unsigned short* __restrict__ vt) {
    __shared__ unsigned short lds[64][66];   // [s][dh], stride 66 (conflict-break)
    const int tid = threadIdx.x;
    const int st = blockIdx.x & (Sc / 64 - 1);   // 32 s-tiles
    const int bh = blockIdx.x >> 5;
    const int b = bh >> 4, h = bh & 15;
#pragma unroll
    for (int i = 0; i < 4; ++i) {
        int srow = (tid >> 4) + i * 16;
        int scol = (tid & 15) * 4;
        float4 x = *(const float4*)(v + ((long)b * Sc + st * 64 + srow) * Dc + h * 64 + scol);
        lds[srow][scol + 0] = f2bf(fmaxf(x.x, 0.f));
        lds[srow][scol + 1] = f2bf(fmaxf(x.y, 0.f));
        lds[srow][scol + 2] = f2bf(fmaxf(x.z, 0.f));
        lds[srow][scol + 3] = f2bf(fmaxf(x.w, 0.f));
    }
    __syncthreads();
#pragma unroll
    for (int i = 0; i < 2; ++i) {
        int dh = (tid >> 3) + i * 32;
        int sc = (tid & 7) * 8;
        union { unsigned short u[8]; s16x8 v8; } o;
#pragma unroll
        for (int j = 0; j < 8; ++j) o.u[j] = lds[sc + j][dh];
        *(s16x8*)(vt + ((long)bh * 64 + dh) * Sc + st * 64 + sc) = o.v8;
    }
}

// plain fp32->bf16 (for W)
__global__ __launch_bounds__(256) void cvt_w(const float* __restrict__ src,
                                             unsigned short* __restrict__ dst) {
    long i = ((long)blockIdx.x * blockDim.x + threadIdx.x) * 4;
    if (i >= (long)Dc * Dc) return;
    float4 v = *reinterpret_cast<const float4*>(src + i);
    ushort4 w;
    w.x = f2bf(v.x); w.y = f2bf(v.y); w.z = f2bf(v.z); w.w = f2bf(v.w);
    *reinterpret_cast<ushort4*>(dst + i) = w;
}

// Flash attention, swapped-operand, 32x32x16 MFMA, fully in-lane softmax.
// Static softmax max (q,k ReLU'd => exp2-domain scores in [0,~7.2], P in [1,150]).
// 1 wave/block, QBLK=32, KVBLK=32. XCD swizzle: 256 consecutive jobs/XCD.
// S^T = K*Q^T : C col = q = l&31, row = kv = (reg&3)+8*(reg>>2)+4*(l>>5).
// P lane-local -> cvt_pk pairs -> permlane32_swap builds PV B-frags (no LDS).
// O^T = V^T*P^T : C col = q = l&31 (denominator lane-aligned), row = dh.
__global__ __launch_bounds__(64) void attn32w(const unsigned short* __restrict__ qh,
                                              const unsigned short* __restrict__ kh,
                                              const unsigned short* __restrict__ vt,
                                              unsigned short* __restrict__ xout) {
    const int l = threadIdx.x;
    const int r32 = l & 31, hl = l >> 5;
    // XCD swizzle (bijective: 2048 % 8 == 0)
    const int job = (blockIdx.x & 7) * (2048 / 8) + (blockIdx.x >> 3);
    const int qt = job & (Sc / 32 - 1);   // 64 q-blocks per bh
    const int bh = job >> 6;

    const unsigned short* Qp = qh + ((long)bh * Sc + qt * 32) * 64;
    const unsigned short* Kp = kh + (long)bh * Sc * 64;
    const unsigned short* Vp = vt + (long)bh * 64 * Sc;

    // Q^T B-frags: B[k=dh][col=q]: lane holds Q[qt*32+r32][ds*16 + hl*8 + i]
    s16x8 qb[4];
#pragma unroll
    for (int ds = 0; ds < 4; ++ds)
        qb[ds] = *(const s16x8*)(Qp + r32 * 64 + ds * 16 + hl * 8);

    f32x16 acc0 = {0,0,0,0,0,0,0,0,0,0,0,0,0,0,0,0};
    f32x16 acc1 = {0,0,0,0,0,0,0,0,0,0,0,0,0,0,0,0};
    float denom = 0.f;

    auto ldk = [&](int kv0, s16x8* ka) {
#pragma unroll
        for (int ds = 0; ds < 4; ++ds)
            ka[ds] = *(const s16x8*)(Kp + (kv0 + r32) * 64 + ds * 16 + hl * 8);
    };
    auto ldv = [&](int kv0, s16x8* va) {
#pragma unroll
        for (int dt = 0; dt < 2; ++dt)
#pragma unroll
            for (int ks = 0; ks < 2; ++ks)
                va[dt * 2 + ks] = *(const s16x8*)(Vp + (dt * 32 + r32) * Sc + kv0 + ks * 16 + hl * 8);
    };

    auto step = [&](const s16x8* ka, const s16x8* va) {
        f32x16 st = {0,0,0,0,0,0,0,0,0,0,0,0,0,0,0,0};
#pragma unroll
        for (int ds = 0; ds < 4; ++ds)
            st = __builtin_amdgcn_mfma_f32_32x32x16_bf16(ka[ds], qb[ds], st, 0, 0, 0);
        // in-lane softmax numerators: p[reg], kv = (reg&3)+8*(reg>>2)+4*hl
        float p[16];
#pragma unroll
        for (int i = 0; i < 16; ++i) p[i] = fexp2(st[i]);
        denom += (((p[0] + p[1]) + (p[2] + p[3])) + ((p[4] + p[5]) + (p[6] + p[7])))
               + (((p[8] + p[9]) + (p[10] + p[11])) + ((p[12] + p[13]) + (p[14] + p[15])));
        // pack kv-pairs; permlane32_swap builds B-frags for both 16-kv slices
        unsigned a0 = cvtpk(p[0], p[1]),  b0 = cvtpk(p[2], p[3]);
        unsigned c0 = cvtpk(p[4], p[5]),  d0 = cvtpk(p[6], p[7]);
        unsigned a1 = cvtpk(p[8], p[9]),  b1 = cvtpk(p[10], p[11]);
        unsigned c1 = cvtpk(p[12], p[13]), d1 = cvtpk(p[14], p[15]);
        plswap(a0, c0); plswap(b0, d0);   // -> words {a0,b0,c0,d0} = P^T kv 0..15
        plswap(a1, c1); plswap(b1, d1);   // -> words {a1,b1,c1,d1} = P^T kv 16..31
        union { unsigned w[4]; s16x8 v8; } B0, B1;
        B0.w[0] = a0; B0.w[1] = b0; B0.w[2] = c0; B0.w[3] = d0;
        B1.w[0] = a1; B1.w[1] = b1; B1.w[2] = c1; B1.w[3] = d1;
        acc0 = __builtin_amdgcn_mfma_f32_32x32x16_bf16(va[0], B0.v8, acc0, 0, 0, 0);
        acc0 = __builtin_amdgcn_mfma_f32_32x32x16_bf16(va[1], B1.v8, acc0, 0, 0, 0);
        acc1 = __builtin_amdgcn_mfma_f32_32x32x16_bf16(va[2], B0.v8, acc1, 0, 0, 0);
        acc1 = __builtin_amdgcn_mfma_f32_32x32x16_bf16(va[3], B1.v8, acc1, 0, 0, 0);
    };

    // register double-buffered main loop (prefetch next kv-tile during compute)
    s16x8 kaA[4], vaA[4], kaB[4], vaB[4];
    ldk(0, kaA); ldv(0, vaA);
    for (int t = 0; t < Sc / 32; t += 2) {
        ldk((t + 1) * 32, kaB); ldv((t + 1) * 32, vaB);
        step(kaA, vaA);
        int n2 = ((t + 2) & (Sc / 32 - 1)) * 32;   // wraps to 0 on last iter (harmless)
        ldk(n2, kaA); ldv(n2, vaA);
        step(kaB, vaB);
    }

    // epilogue: denominator = own half + other lane-half; q = l&31 aligned with C cols
    float dn = denom + __shfl_xor(denom, 32);
    const float inv = 1.0f / dn;
    const int b = bh >> 4, h = bh & 15;
    unsigned short* Xrow = xout + ((long)b * Sc + qt * 32 + r32) * Dc + h * 64;
#pragma unroll
    for (int dt = 0; dt < 2; ++dt) {
        const f32x16& A = dt ? acc1 : acc0;
#pragma unroll
        for (int rg = 0; rg < 4; ++rg) {
            unsigned wlo = cvtpk(A[rg * 4 + 0] * inv, A[rg * 4 + 1] * inv);
            unsigned whi = cvtpk(A[rg * 4 + 2] * inv, A[rg * 4 + 3] * inv);
            uint2 wv; wv.x = wlo; wv.y = whi;
            *reinterpret_cast<uint2*>(Xrow + dt * 32 + rg * 8 + hl * 4) = wv;
        }
    }
}

// Output projection: out = relu(X @ W^T + b). 4 waves/block, 64x64 tile.
__global__ __launch_bounds__(256) void proj64(const unsigned short* __restrict__ X,
                                              const unsigned short* __restrict__ Wb,
                                              const float* __restrict__ bias,
                                              float* __restrict__ out) {
    const int l = threadIdx.x & 63, wv = threadIdx.x >> 6;
    const int r = l & 15, g = l >> 4;
    const int nb = blockIdx.x & 15;   // N/64
    const int mb = blockIdx.x >> 4;   // M/64
    const unsigned short* Xp = X + ((long)(mb * 64 + wv * 16 + r)) * Dc;
    const unsigned short* W0 = Wb + ((long)(nb * 64 + r)) * Dc;
    f32x4 acc[4];
#pragma unroll
    for (int nt = 0; nt < 4; ++nt) acc[nt] = (f32x4){0.f, 0.f, 0.f, 0.f};
#pragma unroll 2
    for (int k = 0; k < Dc; k += 32) {
        s16x8 a = *(const s16x8*)(Xp + k + g * 8);
#pragma unroll
        for (int nt = 0; nt < 4; ++nt) {
            s16x8 bf = *(const s16x8*)(W0 + (long)nt * 16 * Dc + k + g * 8);
            acc[nt] = __builtin_amdgcn_mfma_f32_16x16x32_bf16(a, bf, acc[nt], 0, 0, 0);
        }
    }
#pragma unroll
    for (int nt = 0; nt < 4; ++nt) {
        const float bv = bias[nb * 64 + nt * 16 + r];
#pragma unroll
        for (int j = 0; j < 4; ++j)
            out[((long)(mb * 64 + wv * 16 + g * 4 + j)) * Dc + nb * 64 + nt * 16 + r] =
                fmaxf(acc[nt][j] + bv, 0.f);
    }
}

extern "C" void kernel_launch(void* const* d_in, const int* in_sizes, int n_in,
                              void* d_out, int out_size, void* d_ws, size_t ws_size,
                              hipStream_t stream) {
    const float* q    = (const float*)d_in[0];
    const float* k    = (const float*)d_in[1];
    const float* v    = (const float*)d_in[2];
    const float* w    = (const float*)d_in[3];
    const float* bias = (const float*)d_in[4];
    float* out = (float*)d_out;

    unsigned short* ws = (unsigned short*)d_ws;
    unsigned short* qh = ws;                   // 4194304 bf16
    unsigned short* kh = qh + 4194304;
    unsigned short* vt = kh + 4194304;         // V^T: [B*H][64][2048]
    unsigned short* wb = vt + 4194304;         // 1048576 bf16
    unsigned short* X  = wb + 1048576;         // 4194304 bf16

    // fold softmax scale (1/sqrt(64)) and log2(e) into Q: scores in exp2 domain
    const float QSCALE = 0.125f * 1.44269504088896340736f;
    relu_cvt_heads<<<4096, 256, 0, stream>>>(q, qh, QSCALE);
    relu_cvt_heads<<<4096, 256, 0, stream>>>(k, kh, 1.0f);
    relu_cvt_vT<<<1024, 256, 0, stream>>>(v, vt);
    cvt_w<<<1024, 256, 0, stream>>>(w, wb);
    attn32w<<<Bc * Hc * (Sc / 32), 64, 0, stream>>>(qh, kh, vt, X);
    proj64<<<(Bc * Sc / 64) * (Dc / 64), 256, 0, stream>>>(X, wb, bias, out);
}

// Round 8
// 136.819 us; speedup vs baseline: 1.6195x; 1.5627x over previous
//
#include <hip/hip_runtime.h>
#include <hip/hip_bf16.h>

#define Bc 2
#define Hc 16
#define Sc 2048
#define Dc 1024

typedef __attribute__((ext_vector_type(8))) short s16x8;
typedef __attribute__((ext_vector_type(4))) float f32x4;
typedef __attribute__((ext_vector_type(16))) float f32x16;

#define AS1 __attribute__((address_space(1)))
#define AS3 __attribute__((address_space(3)))

static __device__ __forceinline__ float fexp2(float x) {
#if __has_builtin(__builtin_amdgcn_exp2f)
    return __builtin_amdgcn_exp2f(x);
#else
    float r; asm("v_exp_f32 %0, %1" : "=v"(r) : "v"(x)); return r;
#endif
}

// pack two f32 -> one u32 of 2 bf16 (RTNE), single instruction (T12)
static __device__ __forceinline__ unsigned cvtpk(float lo, float hi) {
    unsigned r; asm("v_cvt_pk_bf16_f32 %0, %1, %2" : "=v"(r) : "v"(lo), "v"(hi));
    return r;
}

// exchange x.lanes[32:63] <-> y.lanes[0:31] (cross-half move)
static __device__ __forceinline__ void plswap(unsigned &x, unsigned &y) {
#if __has_builtin(__builtin_amdgcn_permlane32_swap)
    typedef __attribute__((ext_vector_type(2))) unsigned int u32x2;
    u32x2 t = __builtin_amdgcn_permlane32_swap(x, y, false, false);
    x = t.x; y = t.y;
#else
    asm volatile("v_permlane32_swap_b32 %0, %1" : "+v"(x), "+v"(y));
#endif
}

static __device__ __forceinline__ unsigned short f2bf(float f) {
    union { float f; unsigned u; } x; x.f = f;
    unsigned r = x.u + 0x7fffu + ((x.u >> 16) & 1u);
    return (unsigned short)(r >> 16);
}

// ReLU + scale + fp32->bf16 + [B,S,D] -> [B*H, S, 64] head-major relayout
__global__ __launch_bounds__(256) void relu_cvt_heads(const float* __restrict__ src,
                                                      unsigned short* __restrict__ dst,
                                                      float scale) {
    long i = ((long)blockIdx.x * blockDim.x + threadIdx.x) * 4;
    if (i >= (long)Bc * Sc * Dc) return;
    int dh = (int)(i & 63);
    int h  = (int)((i >> 6) & (Hc - 1));
    int s  = (int)((i >> 10) & (Sc - 1));
    int b  = (int)(i >> 21);
    float4 v = *reinterpret_cast<const float4*>(src + i);
    long o = (((long)b * Hc + h) * Sc + s) * 64 + dh;
    ushort4 w;
    w.x = f2bf(fmaxf(v.x, 0.f) * scale);
    w.y = f2bf(fmaxf(v.y, 0.f) * scale);
    w.z = f2bf(fmaxf(v.z, 0.f) * scale);
    w.w = f2bf(fmaxf(v.w, 0.f) * scale);
    *reinterpret_cast<ushort4*>(dst + o) = w;
}

// ReLU + cvt + transpose V: [B,S,D] -> VT[B*H][64 dh][S] bf16 (tiled via LDS)
__global__ __launch_bounds__(256) void relu_cvt_vT(const float* __restrict__ v,
                                                   unsigned short* __restrict__ vt) {
    __shared__ unsigned short lds[64][66];   // [s][dh], stride 66 (conflict-break)
    const int tid = threadIdx.x;
    const int st = blockIdx.x & (Sc / 64 - 1);   // 32 s-tiles
    const int bh = blockIdx.x >> 5;
    const int b = bh >> 4, h = bh & 15;
#pragma unroll
    for (int i = 0; i < 4; ++i) {
        int srow = (tid >> 4) + i * 16;
        int scol = (tid & 15) * 4;
        float4 x = *(const float4*)(v + ((long)b * Sc + st * 64 + srow) * Dc + h * 64 + scol);
        lds[srow][scol + 0] = f2bf(fmaxf(x.x, 0.f));
        lds[srow][scol + 1] = f2bf(fmaxf(x.y, 0.f));
        lds[srow][scol + 2] = f2bf(fmaxf(x.z, 0.f));
        lds[srow][scol + 3] = f2bf(fmaxf(x.w, 0.f));
    }
    __syncthreads();
#pragma unroll
    for (int i = 0; i < 2; ++i) {
        int dh = (tid >> 3) + i * 32;
        int sc = (tid & 7) * 8;
        union { unsigned short u[8]; s16x8 v8; } o;
#pragma unroll
        for (int j = 0; j < 8; ++j) o.u[j] = lds[sc + j][dh];
        *(s16x8*)(vt + ((long)bh * 64 + dh) * Sc + st * 64 + sc) = o.v8;
    }
}

// plain fp32->bf16 (for W)
__global__ __launch_bounds__(256) void cvt_w(const float* __restrict__ src,
                                             unsigned short* __restrict__ dst) {
    long i = ((long)blockIdx.x * blockDim.x + threadIdx.x) * 4;
    if (i >= (long)Dc * Dc) return;
    float4 v = *reinterpret_cast<const float4*>(src + i);
    ushort4 w;
    w.x = f2bf(v.x); w.y = f2bf(v.y); w.z = f2bf(v.z); w.w = f2bf(v.w);
    *reinterpret_cast<ushort4*>(dst + i) = w;
}

// Flash attention: 4 waves/block, each wave owns a DISTINCT 32-q tile; K/V
// staged to LDS once per block via global_load_lds (async, width=16),
// double-buffered, KVBLK=64. XOR-swizzle (chunk ^= row&7) applied as
// linear-LDS-dest + inverse-swizzled global source + swizzled ds_read.
// Math (proven r7): S^T = K*Q^T 32x32x16; static-max exp2 softmax in-lane;
// cvt_pk + permlane32_swap builds PV B-frags; O^T = V^T*P^T.
__global__ __launch_bounds__(256, 2) void attn_lds(const unsigned short* __restrict__ qh,
                                                   const unsigned short* __restrict__ kh,
                                                   const unsigned short* __restrict__ vt,
                                                   unsigned short* __restrict__ xout) {
    __shared__ unsigned short Klds[2][64 * 64];  // [kv][dh], 128B rows, swizzled chunks
    __shared__ unsigned short Vlds[2][64 * 64];  // [dh][kv], 128B rows, swizzled chunks

    const int tid = threadIdx.x;
    const int l = tid & 63, w = tid >> 6;
    const int r32 = l & 31, hl = l >> 5;
    // XCD swizzle: 512 blocks -> 64 consecutive jobs (4 bh, 2MB K/V) per XCD
    const int job = (blockIdx.x & 7) * 64 + (blockIdx.x >> 3);
    const int qb = job & 15;              // 16 q-super-blocks (128 q) per bh
    const int bh = job >> 4;

    const unsigned short* Qp = qh + ((long)bh * Sc + qb * 128 + w * 32) * 64;
    const unsigned short* Kp = kh + (long)bh * Sc * 64;
    const unsigned short* Vp = vt + (long)bh * 64 * Sc;

    // Q^T B-frags: lane holds Q[q0 + r32][ds*16 + hl*8 + i]
    s16x8 qbf[4];
#pragma unroll
    for (int ds = 0; ds < 4; ++ds)
        qbf[ds] = *(const s16x8*)(Qp + r32 * 64 + ds * 16 + hl * 8);

    f32x16 acc0 = {0,0,0,0,0,0,0,0,0,0,0,0,0,0,0,0};
    f32x16 acc1 = {0,0,0,0,0,0,0,0,0,0,0,0,0,0,0,0};
    float denom = 0.f;

    // async stage of one 64-kv tile: 512 K-chunks + 512 V-chunks (16B each),
    // thread t handles chunks {w*64+l, w*64+256+l}. LDS dest linear; global
    // source chunk = cc ^ (row&7) (involution with the read-side swizzle).
    auto stage = [&](int buf, int kv0) {
#pragma unroll
        for (int j = 0; j < 2; ++j) {
            const int cbase = w * 64 + j * 256;
            const int chunk = cbase + l;
            const int row = chunk >> 3, cc = chunk & 7;
            const int scc = cc ^ (row & 7);
            const unsigned short* ksrc = Kp + (long)(kv0 + row) * 64 + scc * 8;
            const unsigned short* vsrc = Vp + (long)row * Sc + kv0 + scc * 8;
            __builtin_amdgcn_global_load_lds((const AS1 unsigned int*)(const void*)ksrc,
                                             (AS3 unsigned int*)(void*)&Klds[buf][cbase * 8],
                                             16, 0, 0);
            __builtin_amdgcn_global_load_lds((const AS1 unsigned int*)(const void*)vsrc,
                                             (AS3 unsigned int*)(void*)&Vlds[buf][cbase * 8],
                                             16, 0, 0);
        }
    };

    auto compute = [&](int buf) {
        const unsigned short* KB = &Klds[buf][0];
        const unsigned short* VB = &Vlds[buf][0];
        unsigned Bw[4][4];   // [slice s][word] PV B-frags for kv slices of 16
#pragma unroll
        for (int kt = 0; kt < 2; ++kt) {
            f32x16 st = {0,0,0,0,0,0,0,0,0,0,0,0,0,0,0,0};
#pragma unroll
            for (int ds = 0; ds < 4; ++ds) {
                const int row = kt * 32 + r32;
                const int cc = ((ds * 2 + hl) ^ (row & 7));
                s16x8 ka = *(const s16x8*)(KB + row * 64 + cc * 8);
                st = __builtin_amdgcn_mfma_f32_32x32x16_bf16(ka, qbf[ds], st, 0, 0, 0);
            }
            float p[16];
#pragma unroll
            for (int i = 0; i < 16; ++i) p[i] = fexp2(st[i]);
            denom += (((p[0] + p[1]) + (p[2] + p[3])) + ((p[4] + p[5]) + (p[6] + p[7])))
                   + (((p[8] + p[9]) + (p[10] + p[11])) + ((p[12] + p[13]) + (p[14] + p[15])));
            unsigned a0 = cvtpk(p[0], p[1]),   b0 = cvtpk(p[2], p[3]);
            unsigned c0 = cvtpk(p[4], p[5]),   d0 = cvtpk(p[6], p[7]);
            unsigned a1 = cvtpk(p[8], p[9]),   b1 = cvtpk(p[10], p[11]);
            unsigned c1 = cvtpk(p[12], p[13]), d1 = cvtpk(p[14], p[15]);
            plswap(a0, c0); plswap(b0, d0);   // slice kt*2+0 = kv kt*32+0..15
            plswap(a1, c1); plswap(b1, d1);   // slice kt*2+1 = kv kt*32+16..31
            Bw[kt * 2 + 0][0] = a0; Bw[kt * 2 + 0][1] = b0;
            Bw[kt * 2 + 0][2] = c0; Bw[kt * 2 + 0][3] = d0;
            Bw[kt * 2 + 1][0] = a1; Bw[kt * 2 + 1][1] = b1;
            Bw[kt * 2 + 1][2] = c1; Bw[kt * 2 + 1][3] = d1;
        }
#pragma unroll
        for (int dt = 0; dt < 2; ++dt) {
#pragma unroll
            for (int s = 0; s < 4; ++s) {
                const int row = dt * 32 + r32;
                const int cc = ((s * 2 + hl) ^ (row & 7));
                s16x8 va = *(const s16x8*)(VB + row * 64 + cc * 8);
                union { unsigned u[4]; s16x8 v8; } bp;
                bp.u[0] = Bw[s][0]; bp.u[1] = Bw[s][1];
                bp.u[2] = Bw[s][2]; bp.u[3] = Bw[s][3];
                if (dt == 0)
                    acc0 = __builtin_amdgcn_mfma_f32_32x32x16_bf16(va, bp.v8, acc0, 0, 0, 0);
                else
                    acc1 = __builtin_amdgcn_mfma_f32_32x32x16_bf16(va, bp.v8, acc1, 0, 0, 0);
            }
        }
    };

    // 2-phase pipeline: stage(next) || compute(cur); one barrier per tile
    stage(0, 0);
    __syncthreads();
    int cur = 0;
    for (int t = 0; t < Sc / 64 - 1; ++t) {
        stage(cur ^ 1, (t + 1) * 64);
        compute(cur);
        __syncthreads();
        cur ^= 1;
    }
    compute(cur);

    // epilogue: denominator = own half + other lane-half; q = l&31 = C cols
    float dn = denom + __shfl_xor(denom, 32);
    const float inv = 1.0f / dn;
    const int b = bh >> 4, h = bh & 15;
    unsigned short* Xrow = xout + ((long)b * Sc + qb * 128 + w * 32 + r32) * Dc + h * 64;
#pragma unroll
    for (int dt = 0; dt < 2; ++dt) {
        const f32x16& A = dt ? acc1 : acc0;
#pragma unroll
        for (int rg = 0; rg < 4; ++rg) {
            unsigned wlo = cvtpk(A[rg * 4 + 0] * inv, A[rg * 4 + 1] * inv);
            unsigned whi = cvtpk(A[rg * 4 + 2] * inv, A[rg * 4 + 3] * inv);
            uint2 wv; wv.x = wlo; wv.y = whi;
            *reinterpret_cast<uint2*>(Xrow + dt * 32 + rg * 8 + hl * 4) = wv;
        }
    }
}

// Output projection: out = relu(X @ W^T + b). 4 waves/block, 64x64 tile.
__global__ __launch_bounds__(256) void proj64(const unsigned short* __restrict__ X,
                                              const unsigned short* __restrict__ Wb,
                                              const float* __restrict__ bias,
                                              float* __restrict__ out) {
    const int l = threadIdx.x & 63, wv = threadIdx.x >> 6;
    const int r = l & 15, g = l >> 4;
    const int nb = blockIdx.x & 15;   // N/64
    const int mb = blockIdx.x >> 4;   // M/64
    const unsigned short* Xp = X + ((long)(mb * 64 + wv * 16 + r)) * Dc;
    const unsigned short* W0 = Wb + ((long)(nb * 64 + r)) * Dc;
    f32x4 acc[4];
#pragma unroll
    for (int nt = 0; nt < 4; ++nt) acc[nt] = (f32x4){0.f, 0.f, 0.f, 0.f};
#pragma unroll 2
    for (int k = 0; k < Dc; k += 32) {
        s16x8 a = *(const s16x8*)(Xp + k + g * 8);
#pragma unroll
        for (int nt = 0; nt < 4; ++nt) {
            s16x8 bf = *(const s16x8*)(W0 + (long)nt * 16 * Dc + k + g * 8);
            acc[nt] = __builtin_amdgcn_mfma_f32_16x16x32_bf16(a, bf, acc[nt], 0, 0, 0);
        }
    }
#pragma unroll
    for (int nt = 0; nt < 4; ++nt) {
        const float bv = bias[nb * 64 + nt * 16 + r];
#pragma unroll
        for (int j = 0; j < 4; ++j)
            out[((long)(mb * 64 + wv * 16 + g * 4 + j)) * Dc + nb * 64 + nt * 16 + r] =
                fmaxf(acc[nt][j] + bv, 0.f);
    }
}

extern "C" void kernel_launch(void* const* d_in, const int* in_sizes, int n_in,
                              void* d_out, int out_size, void* d_ws, size_t ws_size,
                              hipStream_t stream) {
    const float* q    = (const float*)d_in[0];
    const float* k    = (const float*)d_in[1];
    const float* v    = (const float*)d_in[2];
    const float* w    = (const float*)d_in[3];
    const float* bias = (const float*)d_in[4];
    float* out = (float*)d_out;

    unsigned short* ws = (unsigned short*)d_ws;
    unsigned short* qh = ws;                   // 4194304 bf16
    unsigned short* kh = qh + 4194304;
    unsigned short* vt = kh + 4194304;         // V^T: [B*H][64][2048]
    unsigned short* wb = vt + 4194304;         // 1048576 bf16
    unsigned short* X  = wb + 1048576;         // 4194304 bf16

    // fold softmax scale (1/sqrt(64)) and log2(e) into Q: scores in exp2 domain
    const float QSCALE = 0.125f * 1.44269504088896340736f;
    relu_cvt_heads<<<4096, 256, 0, stream>>>(q, qh, QSCALE);
    relu_cvt_heads<<<4096, 256, 0, stream>>>(k, kh, 1.0f);
    relu_cvt_vT<<<1024, 256, 0, stream>>>(v, vt);
    cvt_w<<<1024, 256, 0, stream>>>(w, wb);
    attn_lds<<<Bc * Hc * (Sc / 128), 256, 0, stream>>>(qh, kh, vt, X);
    proj64<<<(Bc * Sc / 64) * (Dc / 64), 256, 0, stream>>>(X, wb, bias, out);
}

// Round 9
// 83.213 us; speedup vs baseline: 2.6628x; 1.6442x over previous
//
#include <hip/hip_runtime.h>
#include <hip/hip_bf16.h>

#define Bc 2
#define Hc 16
#define Sc 2048
#define Dc 1024

typedef __attribute__((ext_vector_type(8))) short s16x8;
typedef __attribute__((ext_vector_type(4))) float f32x4;
typedef __attribute__((ext_vector_type(16))) float f32x16;

#define AS1 __attribute__((address_space(1)))
#define AS3 __attribute__((address_space(3)))

static __device__ __forceinline__ float fexp2(float x) {
#if __has_builtin(__builtin_amdgcn_exp2f)
    return __builtin_amdgcn_exp2f(x);
#else
    float r; asm("v_exp_f32 %0, %1" : "=v"(r) : "v"(x)); return r;
#endif
}

// pack two f32 -> one u32 of 2 bf16 (RTNE), single instruction (T12)
static __device__ __forceinline__ unsigned cvtpk(float lo, float hi) {
    unsigned r; asm("v_cvt_pk_bf16_f32 %0, %1, %2" : "=v"(r) : "v"(lo), "v"(hi));
    return r;
}

// exchange x.lanes[32:63] <-> y.lanes[0:31] (cross-half move)
static __device__ __forceinline__ void plswap(unsigned &x, unsigned &y) {
#if __has_builtin(__builtin_amdgcn_permlane32_swap)
    typedef __attribute__((ext_vector_type(2))) unsigned int u32x2;
    u32x2 t = __builtin_amdgcn_permlane32_swap(x, y, false, false);
    x = t.x; y = t.y;
#else
    asm volatile("v_permlane32_swap_b32 %0, %1" : "+v"(x), "+v"(y));
#endif
}

static __device__ __forceinline__ unsigned short f2bf(float f) {
    union { float f; unsigned u; } x; x.f = f;
    unsigned r = x.u + 0x7fffu + ((x.u >> 16) & 1u);
    return (unsigned short)(r >> 16);
}

// ReLU + scale + fp32->bf16 + [B,S,D] -> [B*H, S, 64] head-major relayout
__global__ __launch_bounds__(256) void relu_cvt_heads(const float* __restrict__ src,
                                                      unsigned short* __restrict__ dst,
                                                      float scale) {
    long i = ((long)blockIdx.x * blockDim.x + threadIdx.x) * 4;
    if (i >= (long)Bc * Sc * Dc) return;
    int dh = (int)(i & 63);
    int h  = (int)((i >> 6) & (Hc - 1));
    int s  = (int)((i >> 10) & (Sc - 1));
    int b  = (int)(i >> 21);
    float4 v = *reinterpret_cast<const float4*>(src + i);
    long o = (((long)b * Hc + h) * Sc + s) * 64 + dh;
    ushort4 w;
    w.x = f2bf(fmaxf(v.x, 0.f) * scale);
    w.y = f2bf(fmaxf(v.y, 0.f) * scale);
    w.z = f2bf(fmaxf(v.z, 0.f) * scale);
    w.w = f2bf(fmaxf(v.w, 0.f) * scale);
    *reinterpret_cast<ushort4*>(dst + o) = w;
}

// ReLU + cvt + transpose V: [B,S,D] -> VT[B*H][64 dh][S] bf16 (tiled via LDS)
__global__ __launch_bounds__(256) void relu_cvt_vT(const float* __restrict__ v,
                                                   unsigned short* __restrict__ vt) {
    __shared__ unsigned short lds[64][66];   // [s][dh], stride 66 (conflict-break)
    const int tid = threadIdx.x;
    const int st = blockIdx.x & (Sc / 64 - 1);   // 32 s-tiles
    const int bh = blockIdx.x >> 5;
    const int b = bh >> 4, h = bh & 15;
#pragma unroll
    for (int i = 0; i < 4; ++i) {
        int srow = (tid >> 4) + i * 16;
        int scol = (tid & 15) * 4;
        float4 x = *(const float4*)(v + ((long)b * Sc + st * 64 + srow) * Dc + h * 64 + scol);
        lds[srow][scol + 0] = f2bf(fmaxf(x.x, 0.f));
        lds[srow][scol + 1] = f2bf(fmaxf(x.y, 0.f));
        lds[srow][scol + 2] = f2bf(fmaxf(x.z, 0.f));
        lds[srow][scol + 3] = f2bf(fmaxf(x.w, 0.f));
    }
    __syncthreads();
#pragma unroll
    for (int i = 0; i < 2; ++i) {
        int dh = (tid >> 3) + i * 32;
        int sc = (tid & 7) * 8;
        union { unsigned short u[8]; s16x8 v8; } o;
#pragma unroll
        for (int j = 0; j < 8; ++j) o.u[j] = lds[sc + j][dh];
        *(s16x8*)(vt + ((long)bh * 64 + dh) * Sc + st * 64 + sc) = o.v8;
    }
}

// plain fp32->bf16 (for W)
__global__ __launch_bounds__(256) void cvt_w(const float* __restrict__ src,
                                             unsigned short* __restrict__ dst) {
    long i = ((long)blockIdx.x * blockDim.x + threadIdx.x) * 4;
    if (i >= (long)Dc * Dc) return;
    float4 v = *reinterpret_cast<const float4*>(src + i);
    ushort4 w;
    w.x = f2bf(v.x); w.y = f2bf(v.y); w.z = f2bf(v.z); w.w = f2bf(v.w);
    *reinterpret_cast<ushort4*>(dst + i) = w;
}

// Flash attention: 4 waves/block, each wave owns a DISTINCT 32-q tile; K/V
// staged to LDS once per block via global_load_lds (async, width=16),
// double-buffered, KVBLK=64. XOR-swizzle (chunk ^= row&7) applied as
// linear-LDS-dest + inverse-swizzled global source + swizzled ds_read.
// Math: S^T = K*Q^T 32x32x16; static-max exp2 softmax in-lane;
// cvt_pk + permlane32_swap builds PV B-frags; O^T = V^T*P^T.
__global__ __launch_bounds__(256, 2) void attn_lds(const unsigned short* __restrict__ qh,
                                                   const unsigned short* __restrict__ kh,
                                                   const unsigned short* __restrict__ vt,
                                                   unsigned short* __restrict__ xout) {
    __shared__ unsigned short Klds[2][64 * 64];  // [kv][dh], 128B rows, swizzled chunks
    __shared__ unsigned short Vlds[2][64 * 64];  // [dh][kv], 128B rows, swizzled chunks

    const int tid = threadIdx.x;
    const int l = tid & 63, w = tid >> 6;
    const int r32 = l & 31, hl = l >> 5;
    // XCD swizzle: 512 blocks -> 64 consecutive jobs (4 bh, 2MB K/V) per XCD
    const int job = (blockIdx.x & 7) * 64 + (blockIdx.x >> 3);
    const int qb = job & 15;              // 16 q-super-blocks (128 q) per bh
    const int bh = job >> 4;

    const unsigned short* Qp = qh + ((long)bh * Sc + qb * 128 + w * 32) * 64;
    const unsigned short* Kp = kh + (long)bh * Sc * 64;
    const unsigned short* Vp = vt + (long)bh * 64 * Sc;

    // Q^T B-frags: lane holds Q[q0 + r32][ds*16 + hl*8 + i]
    s16x8 qbf[4];
#pragma unroll
    for (int ds = 0; ds < 4; ++ds)
        qbf[ds] = *(const s16x8*)(Qp + r32 * 64 + ds * 16 + hl * 8);

    f32x16 acc0 = {0,0,0,0,0,0,0,0,0,0,0,0,0,0,0,0};
    f32x16 acc1 = {0,0,0,0,0,0,0,0,0,0,0,0,0,0,0,0};
    float denom = 0.f;

    auto stage = [&](int buf, int kv0) {
#pragma unroll
        for (int j = 0; j < 2; ++j) {
            const int cbase = w * 64 + j * 256;
            const int chunk = cbase + l;
            const int row = chunk >> 3, cc = chunk & 7;
            const int scc = cc ^ (row & 7);
            const unsigned short* ksrc = Kp + (long)(kv0 + row) * 64 + scc * 8;
            const unsigned short* vsrc = Vp + (long)row * Sc + kv0 + scc * 8;
            __builtin_amdgcn_global_load_lds((const AS1 unsigned int*)(const void*)ksrc,
                                             (AS3 unsigned int*)(void*)&Klds[buf][cbase * 8],
                                             16, 0, 0);
            __builtin_amdgcn_global_load_lds((const AS1 unsigned int*)(const void*)vsrc,
                                             (AS3 unsigned int*)(void*)&Vlds[buf][cbase * 8],
                                             16, 0, 0);
        }
    };

    auto compute = [&](int buf) {
        const unsigned short* KB = &Klds[buf][0];
        const unsigned short* VB = &Vlds[buf][0];
        unsigned Bw[4][4];   // [slice s][word] PV B-frags for kv slices of 16
#pragma unroll
        for (int kt = 0; kt < 2; ++kt) {
            f32x16 st = {0,0,0,0,0,0,0,0,0,0,0,0,0,0,0,0};
#pragma unroll
            for (int ds = 0; ds < 4; ++ds) {
                const int row = kt * 32 + r32;
                const int cc = ((ds * 2 + hl) ^ (row & 7));
                s16x8 ka = *(const s16x8*)(KB + row * 64 + cc * 8);
                st = __builtin_amdgcn_mfma_f32_32x32x16_bf16(ka, qbf[ds], st, 0, 0, 0);
            }
            float p[16];
#pragma unroll
            for (int i = 0; i < 16; ++i) p[i] = fexp2(st[i]);
            denom += (((p[0] + p[1]) + (p[2] + p[3])) + ((p[4] + p[5]) + (p[6] + p[7])))
                   + (((p[8] + p[9]) + (p[10] + p[11])) + ((p[12] + p[13]) + (p[14] + p[15])));
            unsigned a0 = cvtpk(p[0], p[1]),   b0 = cvtpk(p[2], p[3]);
            unsigned c0 = cvtpk(p[4], p[5]),   d0 = cvtpk(p[6], p[7]);
            unsigned a1 = cvtpk(p[8], p[9]),   b1 = cvtpk(p[10], p[11]);
            unsigned c1 = cvtpk(p[12], p[13]), d1 = cvtpk(p[14], p[15]);
            plswap(a0, c0); plswap(b0, d0);
            plswap(a1, c1); plswap(b1, d1);
            Bw[kt * 2 + 0][0] = a0; Bw[kt * 2 + 0][1] = b0;
            Bw[kt * 2 + 0][2] = c0; Bw[kt * 2 + 0][3] = d0;
            Bw[kt * 2 + 1][0] = a1; Bw[kt * 2 + 1][1] = b1;
            Bw[kt * 2 + 1][2] = c1; Bw[kt * 2 + 1][3] = d1;
        }
#pragma unroll
        for (int dt = 0; dt < 2; ++dt) {
#pragma unroll
            for (int s = 0; s < 4; ++s) {
                const int row = dt * 32 + r32;
                const int cc = ((s * 2 + hl) ^ (row & 7));
                s16x8 va = *(const s16x8*)(VB + row * 64 + cc * 8);
                union { unsigned u[4]; s16x8 v8; } bp;
                bp.u[0] = Bw[s][0]; bp.u[1] = Bw[s][1];
                bp.u[2] = Bw[s][2]; bp.u[3] = Bw[s][3];
                if (dt == 0)
                    acc0 = __builtin_amdgcn_mfma_f32_32x32x16_bf16(va, bp.v8, acc0, 0, 0, 0);
                else
                    acc1 = __builtin_amdgcn_mfma_f32_32x32x16_bf16(va, bp.v8, acc1, 0, 0, 0);
            }
        }
    };

    stage(0, 0);
    __syncthreads();
    int cur = 0;
    for (int t = 0; t < Sc / 64 - 1; ++t) {
        stage(cur ^ 1, (t + 1) * 64);
        compute(cur);
        __syncthreads();
        cur ^= 1;
    }
    compute(cur);

    float dn = denom + __shfl_xor(denom, 32);
    const float inv = 1.0f / dn;
    const int b = bh >> 4, h = bh & 15;
    unsigned short* Xrow = xout + ((long)b * Sc + qb * 128 + w * 32 + r32) * Dc + h * 64;
#pragma unroll
    for (int dt = 0; dt < 2; ++dt) {
        const f32x16& A = dt ? acc1 : acc0;
#pragma unroll
        for (int rg = 0; rg < 4; ++rg) {
            unsigned wlo = cvtpk(A[rg * 4 + 0] * inv, A[rg * 4 + 1] * inv);
            unsigned whi = cvtpk(A[rg * 4 + 2] * inv, A[rg * 4 + 3] * inv);
            uint2 wv; wv.x = wlo; wv.y = whi;
            *reinterpret_cast<uint2*>(Xrow + dt * 32 + rg * 8 + hl * 4) = wv;
        }
    }
}

// Output projection: out = relu(X @ W^T + b), X:[4096x1024] bf16, W row-major.
// Tiled LDS GEMM, same pipeline as attn_lds: BM=128, BN=64, BK=64, 4 waves
// (each a 32x64 strip = 2x mfma_f32_32x32x16 per k-step), double-buffered
// global_load_lds staging with the cc^=row&7 involution swizzle, one barrier
// per K-stage, 16 stages. Grid 512 = 2 blocks/CU, XCD-swizzled.
__global__ __launch_bounds__(256, 2) void proj128(const unsigned short* __restrict__ X,
                                                  const unsigned short* __restrict__ Wb,
                                                  const float* __restrict__ bias,
                                                  float* __restrict__ out) {
    __shared__ unsigned short Xlds[2][128 * 64];  // [m][k], 128B rows, swizzled chunks
    __shared__ unsigned short Wlds[2][64 * 64];   // [n][k], 128B rows, swizzled chunks

    const int tid = threadIdx.x;
    const int l = tid & 63, w = tid >> 6;
    const int r32 = l & 31, hl = l >> 5;
    // XCD swizzle (bijective: 512 % 8 == 0): 64 consecutive jobs per XCD
    // -> 4 mb X-tiles (1MB) + all of W (2MB) resident per XCD L2.
    const int job = (blockIdx.x & 7) * 64 + (blockIdx.x >> 3);
    const int nb = job & 15;    // 16 n-tiles of 64
    const int mb = job >> 4;    // 32 m-tiles of 128

    const unsigned short* Xp = X + (long)mb * 128 * Dc;
    const unsigned short* Wp = Wb + (long)nb * 64 * Dc;

    f32x16 acc0 = {0,0,0,0,0,0,0,0,0,0,0,0,0,0,0,0};
    f32x16 acc1 = {0,0,0,0,0,0,0,0,0,0,0,0,0,0,0,0};

    // stage one BK=64 slab: X 128x64 (1024 chunks) + W 64x64 (512 chunks)
    auto stage = [&](int buf, int k0) {
#pragma unroll
        for (int j = 0; j < 4; ++j) {
            const int cbase = w * 256 + j * 64;
            const int chunk = cbase + l;
            const int row = chunk >> 3, cc = chunk & 7;
            const int scc = cc ^ (row & 7);
            const unsigned short* xsrc = Xp + (long)row * Dc + k0 + scc * 8;
            __builtin_amdgcn_global_load_lds((const AS1 unsigned int*)(const void*)xsrc,
                                             (AS3 unsigned int*)(void*)&Xlds[buf][cbase * 8],
                                             16, 0, 0);
        }
#pragma unroll
        for (int j = 0; j < 2; ++j) {
            const int cbase = w * 128 + j * 64;
            const int chunk = cbase + l;
            const int row = chunk >> 3, cc = chunk & 7;
            const int scc = cc ^ (row & 7);
            const unsigned short* wsrc = Wp + (long)row * Dc + k0 + scc * 8;
            __builtin_amdgcn_global_load_lds((const AS1 unsigned int*)(const void*)wsrc,
                                             (AS3 unsigned int*)(void*)&Wlds[buf][cbase * 8],
                                             16, 0, 0);
        }
    };

    auto compute = [&](int buf) {
        const unsigned short* XB = &Xlds[buf][0];
        const unsigned short* WB = &Wlds[buf][0];
#pragma unroll
        for (int ks = 0; ks < 4; ++ks) {   // 4 k-subs of 16 within BK=64
            const int arow = w * 32 + r32;
            const int acc_ = ((ks * 2 + hl) ^ (arow & 7));
            s16x8 af = *(const s16x8*)(XB + arow * 64 + acc_ * 8);
#pragma unroll
            for (int nt = 0; nt < 2; ++nt) {
                const int brow = nt * 32 + r32;
                const int bcc = ((ks * 2 + hl) ^ (brow & 7));
                s16x8 bf = *(const s16x8*)(WB + brow * 64 + bcc * 8);
                if (nt == 0)
                    acc0 = __builtin_amdgcn_mfma_f32_32x32x16_bf16(af, bf, acc0, 0, 0, 0);
                else
                    acc1 = __builtin_amdgcn_mfma_f32_32x32x16_bf16(af, bf, acc1, 0, 0, 0);
            }
        }
    };

    stage(0, 0);
    __syncthreads();
    int cur = 0;
    for (int t = 0; t < Dc / 64 - 1; ++t) {
        stage(cur ^ 1, (t + 1) * 64);
        compute(cur);
        __syncthreads();
        cur ^= 1;
    }
    compute(cur);

    // epilogue: C row m = (reg&3)+8*(reg>>2)+4*hl (+ wave strip), col n = r32
#pragma unroll
    for (int nt = 0; nt < 2; ++nt) {
        const f32x16& A = nt ? acc1 : acc0;
        const float bv = bias[nb * 64 + nt * 32 + r32];
#pragma unroll
        for (int j = 0; j < 16; ++j) {
            const int m = (j & 3) + 8 * (j >> 2) + 4 * hl;
            out[((long)(mb * 128 + w * 32 + m)) * Dc + nb * 64 + nt * 32 + r32] =
                fmaxf(A[j] + bv, 0.f);
        }
    }
}

extern "C" void kernel_launch(void* const* d_in, const int* in_sizes, int n_in,
                              void* d_out, int out_size, void* d_ws, size_t ws_size,
                              hipStream_t stream) {
    const float* q    = (const float*)d_in[0];
    const float* k    = (const float*)d_in[1];
    const float* v    = (const float*)d_in[2];
    const float* w    = (const float*)d_in[3];
    const float* bias = (const float*)d_in[4];
    float* out = (float*)d_out;

    unsigned short* ws = (unsigned short*)d_ws;
    unsigned short* qh = ws;                   // 4194304 bf16
    unsigned short* kh = qh + 4194304;
    unsigned short* vt = kh + 4194304;         // V^T: [B*H][64][2048]
    unsigned short* wb = vt + 4194304;         // 1048576 bf16
    unsigned short* X  = wb + 1048576;         // 4194304 bf16

    // fold softmax scale (1/sqrt(64)) and log2(e) into Q: scores in exp2 domain
    const float QSCALE = 0.125f * 1.44269504088896340736f;
    relu_cvt_heads<<<4096, 256, 0, stream>>>(q, qh, QSCALE);
    relu_cvt_heads<<<4096, 256, 0, stream>>>(k, kh, 1.0f);
    relu_cvt_vT<<<1024, 256, 0, stream>>>(v, vt);
    cvt_w<<<1024, 256, 0, stream>>>(w, wb);
    attn_lds<<<Bc * Hc * (Sc / 128), 256, 0, stream>>>(qh, kh, vt, X);
    proj128<<<(Bc * Sc / 128) * (Dc / 64), 256, 0, stream>>>(X, wb, bias, out);
}